// Round 10
// baseline (272.114 us; speedup 1.0000x reference)
//
#include <hip/hip_runtime.h>
#include <hip/hip_bf16.h>

typedef unsigned int   u32;
typedef unsigned short u16;
typedef unsigned char  u8;
typedef float f32x2 __attribute__((ext_vector_type(2)));
typedef float f32x4 __attribute__((ext_vector_type(4)));

#define N_NODES 50000
#define C_DIM   128
#define E_EDGES 1600000
#define NUM_IDX 2048

#define CPB 256                    // cols per coarse bucket (key >> 8)
#define NB  196                    // ceil(N/CPB)
#define CAP 9216                   // padded capacity per bucket (mean 8192, sigma ~90)
#define CHK 8192                   // edges per chunk
#define NP  196                    // ceil(E/CHK)
#define PT  512                    // threads for partition-family kernels
#define EPT 16                     // edges per thread in partition (CHK/PT)
#define GB  8                      // nodes per label-matmul block
#define NLB 98                     // label-stripe blocks of 512 (ceil(N/512))

// LESSONS (journal):
// r5: device-scope global atomics on MI355X are HBM-side RMW. Keep hists in LDS.
// r6: f32x4-casting per-g LDS reads in double-unrolled loops -> scratch spill.
// r7: node_msg LDS-issue bound; k-major staging (xsT[k][g]) broadcast b128.
// r8: gather one-shot is L3-random bound (149MB @ 2.7TB/s = 54us).
// r9: split gather into 4 channel-quarter passes: 3.2MB working set fits each
//     XCD's 4MB L2 -> only compulsory misses. srcrow loads nontemporal so the
//     streaming co-tenant doesn't evict the resident quarter.

// K_A: blocks 0..NP-1 partition edges into padded bucket regions (zero-based
// cursors: reservation adds b*CAP). Blocks NP.. do label/id histogram.
__global__ void part_hist_kernel(const int* __restrict__ row, const int* __restrict__ col,
                                 const int* __restrict__ label, const int* __restrict__ id,
                                 int* __restrict__ colCursor, int* __restrict__ rowCursor,
                                 u32* __restrict__ S, u8* __restrict__ Sr,
                                 int* __restrict__ labCnt, int* __restrict__ cnt) {
    __shared__ int hc[NB], hr[NB], bc[NB], br[NB];
    __shared__ int h8[8];
    int t = threadIdx.x;
    if (blockIdx.x >= NP) {
        // ---- label/id histogram branch (98 blocks x 512 threads) ----
        if (t < 8) h8[t] = 0;
        __syncthreads();
        int n = (blockIdx.x - NP) * PT + t;
        if (n < N_NODES) atomicAdd(&h8[label[n]], 1);
        if (n < NUM_IDX) atomicAdd(&cnt[id[n]], 1);   // blocks 0..3 cover 2048 ids
        __syncthreads();
        if (t < 8 && h8[t] > 0) atomicAdd(&labCnt[t], h8[t]);
        return;
    }
    // ---- partition branch ----
    int p = blockIdx.x;
    for (int i = t; i < NB; i += PT) { hc[i] = 0; hr[i] = 0; }
    __syncthreads();
    int e0 = p * CHK, e1 = min(e0 + CHK, E_EDGES);
    int rr[EPT], cc[EPT];
    #pragma unroll
    for (int i = 0; i < EPT; ++i) {
        int e = e0 + t + i * PT;
        if (e < e1) {
            int r = row[e], c = col[e];
            rr[i] = r; cc[i] = c;
            atomicAdd(&hc[c >> 8], 1);
            atomicAdd(&hr[r >> 8], 1);
        }
    }
    __syncthreads();
    for (int i = t; i < NB; i += PT) {
        bc[i] = (hc[i] > 0) ? (i * CAP + atomicAdd(&colCursor[i], hc[i])) : 0;
        br[i] = (hr[i] > 0) ? (i * CAP + atomicAdd(&rowCursor[i], hr[i])) : 0;
    }
    __syncthreads();
    #pragma unroll
    for (int i = 0; i < EPT; ++i) {
        int e = e0 + t + i * PT;
        if (e < e1) {
            int r = rr[i], c = cc[i];
            int pc = atomicAdd(&bc[c >> 8], 1);
            S[pc] = ((u32)r << 8) | (u32)(c & 255);
            int pr = atomicAdd(&br[r >> 8], 1);
            Sr[pr] = (u8)(r & 255);
        }
    }
}

// K_B: blocks 0..NB-1 fine-CSR; NB..2NB-1 degree/dinv; 2NB.. label_fill.
__global__ void csr_fill_kernel(const u32* __restrict__ S, const u8* __restrict__ Sr,
                                const int* __restrict__ colCursor, const int* __restrict__ rowCursor,
                                int* __restrict__ s_beg, int* __restrict__ s_end,
                                u16* __restrict__ srcrow, float* __restrict__ dinv,
                                const int* __restrict__ label, const int* __restrict__ labCnt,
                                int* __restrict__ labOffset, int* __restrict__ nodeByLabel) {
    __shared__ int h[CPB], cur[CPB], sc[CPB];
    __shared__ int h8[8], base8[8], c28[8];
    int t = threadIdx.x;
    if (blockIdx.x >= 2 * NB) {
        // ---- label_fill branch (98 blocks x 512 threads) ----
        if (t < 8) { h8[t] = 0; c28[t] = 0; }
        __syncthreads();
        int n = (blockIdx.x - 2 * NB) * PT + t;
        int l = 0;
        if (n < N_NODES) { l = label[n]; atomicAdd(&h8[l], 1); }
        __syncthreads();
        if (t < 8 && h8[t] > 0) {
            int lb = 0;                          // labBase[l] = prefix of labCnt
            for (int i = 0; i < t; ++i) lb += labCnt[i];
            base8[t] = lb + atomicAdd(&labOffset[t], h8[t]);
        }
        __syncthreads();
        if (n < N_NODES) {
            int pos = base8[l] + atomicAdd(&c28[l], 1);
            nodeByLabel[pos] = n;
        }
        return;
    }
    if (blockIdx.x >= NB) {
        // ---- degree branch: LDS histogram of Sr bucket -> dinv ----
        int b = blockIdx.x - NB;
        if (t < CPB) h[t] = 0;
        __syncthreads();
        int e0 = b * CAP, e1 = b * CAP + rowCursor[b];
        for (int e = e0 + t; e < e1; e += PT) atomicAdd(&h[Sr[e]], 1);
        __syncthreads();
        if (t < CPB) {
            int n = b * CPB + t;
            if (n < N_NODES) dinv[n] = rsqrtf((float)(h[t] + 1));
        }
        return;
    }
    // ---- fine-CSR branch ----
    int b = blockIdx.x;
    if (t < CPB) h[t] = 0;
    __syncthreads();
    int e0 = b * CAP, e1 = b * CAP + colCursor[b];
    for (int e = e0 + t; e < e1; e += PT) atomicAdd(&h[S[e] & 255u], 1);
    __syncthreads();
    if (t < CPB) sc[t] = h[t];
    __syncthreads();
    for (int off = 1; off < CPB; off <<= 1) {
        int v = 0, a = 0;
        if (t < CPB) { v = sc[t]; a = (t >= off) ? sc[t - off] : 0; }
        __syncthreads();
        if (t < CPB) sc[t] = v + a;
        __syncthreads();
    }
    if (t < CPB) {
        int base = (t == 0) ? 0 : sc[t - 1];
        int gcol = b * CPB + t;
        if (gcol < N_NODES) {
            s_beg[gcol] = e0 + base;
            s_end[gcol] = e0 + base + h[t];
        }
        cur[t] = base;
    }
    __syncthreads();
    for (int e = e0 + t; e < e1; e += PT) {
        u32 v = S[e];
        int pos = atomicAdd(&cur[v & 255u], 1);
        srcrow[e0 + pos] = (u16)(v >> 8);
    }
}

// K6: label-grouped node transform -> bf16 messages (r7 k-major staging).
__global__ void node_msg_kernel(const float* __restrict__ x,
                                const int* __restrict__ cnt,
                                const int* __restrict__ label,
                                const float* __restrict__ dinv,
                                const float* __restrict__ W,
                                const float* __restrict__ Wid,
                                const int* __restrict__ nodeByLabel,
                                __hip_bfloat16* __restrict__ msgb) {
    __shared__ float xsT[C_DIM][GB];       // [k][g], 4 KB
    __shared__ int nid[GB], lab[GB], cc[GB];
    int t = threadIdx.x;
    if (t < GB) {
        int n = nodeByLabel[blockIdx.x * GB + t];
        nid[t] = n; lab[t] = label[n]; cc[t] = cnt[n];
    }
    __syncthreads();
    #pragma unroll
    for (int g = 0; g < GB; ++g)
        xsT[t][g] = __builtin_nontemporal_load(x + (size_t)nid[g] * C_DIM + t);
    __syncthreads();
    for (int g = 0; g < GB; ++g) {          // ego update (~4% of nodes)
        int c = cc[g];
        if (c > 0) {
            float acc = 0.f;
            #pragma unroll 8
            for (int k = 0; k < C_DIM; ++k) acc += xsT[k][g] * W[k * C_DIM + t];
            __syncthreads();
            xsT[t][g] += (float)c * acc;
            __syncthreads();
        }
    }
    float res[GB];
    #pragma unroll
    for (int g = 0; g < GB; ++g) res[g] = xsT[t][g];
    if (lab[0] == lab[GB - 1]) {
        int L = lab[0];
        if (L > 0) {
            const float* Wl = Wid + (size_t)(L - 1) * C_DIM * C_DIM;
            float acc[GB];
            #pragma unroll
            for (int g = 0; g < GB; ++g) acc[g] = 0.f;
            for (int k = 0; k < C_DIM; ++k) {
                float w = Wl[k * C_DIM + t];
                f32x4 xv0 = *(const f32x4*)&xsT[k][0];   // broadcast b128
                f32x4 xv1 = *(const f32x4*)&xsT[k][4];   // broadcast b128
                acc[0] += xv0.x * w; acc[1] += xv0.y * w;
                acc[2] += xv0.z * w; acc[3] += xv0.w * w;
                acc[4] += xv1.x * w; acc[5] += xv1.y * w;
                acc[6] += xv1.z * w; acc[7] += xv1.w * w;
            }
            #pragma unroll
            for (int g = 0; g < GB; ++g) res[g] += acc[g];
        }
    } else {
        for (int g = 0; g < GB; ++g) {
            int L = lab[g];
            if (L > 0) {
                const float* Wl = Wid + (size_t)(L - 1) * C_DIM * C_DIM;
                float acc = 0.f;
                #pragma unroll 8
                for (int k = 0; k < C_DIM; ++k) acc += xsT[k][g] * Wl[k * C_DIM + t];
                res[g] += acc;
            }
        }
    }
    #pragma unroll
    for (int g = 0; g < GB; ++g) {
        int n = nid[g];
        msgb[(size_t)n * C_DIM + t] = __float2bfloat16(dinv[n] * res[g]);
    }
}

// K7: gather pass. One wave per dest col, channel-QUARTER per pass (32 ch =
// 64B/node -> 3.2MB working set, L2-resident per XCD). Lane = (g,q):
// g = lane>>2 in [0,16) edge slot, q = lane&3 quarter-uint4. One wave VMEM
// instr covers 16 edges. Reduce slots via shfl_xor(4/8/16/32); lanes 0..3
// store 2x f32x4 (128B per col per pass).
__global__ void gather_pass_kernel(const int* __restrict__ s_beg, const int* __restrict__ s_end,
                                   const u16* __restrict__ srcrow,
                                   const float* __restrict__ dinv,
                                   const u32* __restrict__ m32,   // bf16x2-packed msg
                                   float* __restrict__ out, int pass) {
    int wid  = threadIdx.x >> 6;
    int lane = threadIdx.x & 63;
    int g = lane >> 2;
    int q = lane & 3;
    int c = blockIdx.x * 4 + wid;
    int e0 = s_beg[c], e1 = s_end[c];
    const uint4* m4 = (const uint4*)m32;     // one node = 16 uint4
    const u32 pq = (u32)(pass * 4 + q);      // uint4 index within node's quarter

    float a0[4], a1[4];
    #pragma unroll
    for (int k = 0; k < 4; ++k) { a0[k] = 0.f; a1[k] = 0.f; }

    #define ACC4(U)                                                          \
        a0[0] += __uint_as_float((U).x << 16); a1[0] += __uint_as_float((U).x & 0xffff0000u); \
        a0[1] += __uint_as_float((U).y << 16); a1[1] += __uint_as_float((U).y & 0xffff0000u); \
        a0[2] += __uint_as_float((U).z << 16); a1[2] += __uint_as_float((U).z & 0xffff0000u); \
        a0[3] += __uint_as_float((U).w << 16); a1[3] += __uint_as_float((U).w & 0xffff0000u);

    if (g == 0) {                            // self-loop message (slot 0 only)
        uint4 us = m4[(u32)c * 16u + pq];
        ACC4(us);
    }
    int e = e0;
    for (; e + 32 <= e1; e += 32) {
        u32 r0 = __builtin_nontemporal_load(srcrow + e + g);
        u32 r1 = __builtin_nontemporal_load(srcrow + e + 16 + g);
        uint4 u0 = m4[r0 * 16u + pq];
        uint4 u1 = m4[r1 * 16u + pq];
        ACC4(u0);
        ACC4(u1);
    }
    for (; e + 16 <= e1; e += 16) {
        u32 r0 = __builtin_nontemporal_load(srcrow + e + g);
        uint4 u0 = m4[r0 * 16u + pq];
        ACC4(u0);
    }
    if (e + g < e1) {                        // tail (<16 edges, predicated)
        u32 r0 = srcrow[e + g];
        uint4 u0 = m4[r0 * 16u + pq];
        ACC4(u0);
    }
    #undef ACC4

    // reduce the 16 edge-slot groups (lane bits 2..5); lanes 0..3 keep quarter q
    #pragma unroll
    for (int k = 0; k < 4; ++k) {
        a0[k] += __shfl_xor(a0[k], 4);
        a0[k] += __shfl_xor(a0[k], 8);
        a0[k] += __shfl_xor(a0[k], 16);
        a0[k] += __shfl_xor(a0[k], 32);
        a1[k] += __shfl_xor(a1[k], 4);
        a1[k] += __shfl_xor(a1[k], 8);
        a1[k] += __shfl_xor(a1[k], 16);
        a1[k] += __shfl_xor(a1[k], 32);
    }

    if (lane < 4) {
        float di = dinv[c];
        f32x4 o0, o1;
        o0.x = di * a0[0]; o0.y = di * a1[0]; o0.z = di * a0[1]; o0.w = di * a1[1];
        o1.x = di * a0[2]; o1.y = di * a1[2]; o1.z = di * a0[3]; o1.w = di * a1[3];
        // channels [pass*32 + q*8, +8) of col c
        f32x4* op = (f32x4*)(out + ((size_t)c << 7)) + (pass << 3) + (q << 1);
        __builtin_nontemporal_store(o0, op);
        __builtin_nontemporal_store(o1, op + 1);
    }
}

extern "C" void kernel_launch(void* const* d_in, const int* in_sizes, int n_in,
                              void* d_out, int out_size, void* d_ws, size_t ws_size,
                              hipStream_t stream) {
    const float* x     = (const float*)d_in[0];
    const int*   edge  = (const int*)d_in[1];   // [2][E]
    const int*   id    = (const int*)d_in[2];
    const int*   label = (const int*)d_in[3];
    const float* W     = (const float*)d_in[4];
    const float* Wid   = (const float*)d_in[5];
    float*       out   = (float*)d_out;

    const int* row = edge;
    const int* col = edge + E_EDGES;

    // ws layout:
    // msgb[N*C] bf16 | S[NB*CAP] u32 | srcrow[NB*CAP] u16 | Sr[NB*CAP] u8 |
    // s_beg[N] | s_end[N] | nodeByLabel[N] | dinv[N] f32 |
    // ZERO{ cnt[N] | labCnt[8] | labOffset[8] | colCursor[NB] | rowCursor[NB] }
    __hip_bfloat16* msgb = (__hip_bfloat16*)d_ws;
    u32* S           = (u32*)(msgb + (size_t)N_NODES * C_DIM);
    u16* srcrow      = (u16*)(S + (size_t)NB * CAP);
    u8*  Sr          = (u8*)(srcrow + (size_t)NB * CAP);
    int* s_beg       = (int*)(Sr + (size_t)NB * CAP);
    int* s_end       = s_beg + N_NODES;
    int* nodeByLabel = s_end + N_NODES;
    float* dinv      = (float*)(nodeByLabel + N_NODES);
    int* cnt         = (int*)(dinv + N_NODES);
    int* labCnt      = cnt + N_NODES;
    int* labOffset   = labCnt + 8;
    int* colCursor   = labOffset + 8;
    int* rowCursor   = colCursor + NB;

    hipMemsetAsync(cnt, 0, ((size_t)N_NODES + 16 + 2 * NB) * sizeof(int), stream);

    part_hist_kernel<<<NP + NLB, PT, 0, stream>>>(row, col, label, id,
                                                  colCursor, rowCursor, S, Sr, labCnt, cnt);
    csr_fill_kernel <<<2 * NB + NLB, PT, 0, stream>>>(S, Sr, colCursor, rowCursor,
                                                      s_beg, s_end, srcrow, dinv,
                                                      label, labCnt, labOffset, nodeByLabel);
    node_msg_kernel <<<N_NODES / GB, C_DIM, 0, stream>>>(x, cnt, label, dinv, W, Wid,
                                                         nodeByLabel, msgb);
    for (int pass = 0; pass < 4; ++pass)
        gather_pass_kernel<<<N_NODES / 4, 256, 0, stream>>>(s_beg, s_end, srcrow, dinv,
                                                            (const u32*)msgb, out, pass);
}

// Round 11
// 215.911 us; speedup vs baseline: 1.2603x; 1.2603x over previous
//
#include <hip/hip_runtime.h>
#include <hip/hip_bf16.h>

typedef unsigned int   u32;
typedef unsigned short u16;
typedef unsigned char  u8;
typedef float f32x2 __attribute__((ext_vector_type(2)));
typedef float f32x4 __attribute__((ext_vector_type(4)));

#define N_NODES 50000
#define C_DIM   128
#define E_EDGES 1600000
#define NUM_IDX 2048

#define CPB 256                    // cols per coarse bucket (key >> 8)
#define NB  196                    // ceil(N/CPB)
#define CAP 9216                   // padded capacity per bucket (mean 8192, sigma ~90)
#define CHK 8192                   // edges per chunk
#define NP  196                    // ceil(E/CHK)
#define PT  512                    // threads for partition-family kernels
#define EPT 16                     // edges per thread in partition (CHK/PT)
#define GB  8                      // nodes per label-matmul block
#define NLB 98                     // label-stripe blocks of 512 (ceil(N/512))

// LESSONS (journal):
// r5: device-scope global atomics on MI355X are HBM-side RMW. Keep hists in LDS.
// r6: f32x4-casting per-g LDS reads in double-unrolled loops -> scratch spill.
// r7: node_msg LDS-issue bound; k-major staging (xsT[k][g]) broadcast b128.
// r8: gather one-shot is L3-random bound (149MB @ 2.7TB/s = 54us floor).
// r10: 4-pass channel-split gather REGRESSED (+46us): quarter doesn't stay
//      L2-resident vs streaming co-tenants across 8 XCDs; srcrow re-read x4.
//      Single-pass gather is the floor. node_msg: 2 waves/block duplicated
//      every LDS broadcast -> use 1 wave x 2 channels/thread.

// K_A: blocks 0..NP-1 partition edges into padded bucket regions (zero-based
// cursors: reservation adds b*CAP). Blocks NP.. do label/id histogram.
__global__ void part_hist_kernel(const int* __restrict__ row, const int* __restrict__ col,
                                 const int* __restrict__ label, const int* __restrict__ id,
                                 int* __restrict__ colCursor, int* __restrict__ rowCursor,
                                 u32* __restrict__ S, u8* __restrict__ Sr,
                                 int* __restrict__ labCnt, int* __restrict__ cnt) {
    __shared__ int hc[NB], hr[NB], bc[NB], br[NB];
    __shared__ int h8[8];
    int t = threadIdx.x;
    if (blockIdx.x >= NP) {
        // ---- label/id histogram branch (98 blocks x 512 threads) ----
        if (t < 8) h8[t] = 0;
        __syncthreads();
        int n = (blockIdx.x - NP) * PT + t;
        if (n < N_NODES) atomicAdd(&h8[label[n]], 1);
        if (n < NUM_IDX) atomicAdd(&cnt[id[n]], 1);   // blocks 0..3 cover 2048 ids
        __syncthreads();
        if (t < 8 && h8[t] > 0) atomicAdd(&labCnt[t], h8[t]);
        return;
    }
    // ---- partition branch ----
    int p = blockIdx.x;
    for (int i = t; i < NB; i += PT) { hc[i] = 0; hr[i] = 0; }
    __syncthreads();
    int e0 = p * CHK, e1 = min(e0 + CHK, E_EDGES);
    int rr[EPT], cc[EPT];
    #pragma unroll
    for (int i = 0; i < EPT; ++i) {
        int e = e0 + t + i * PT;
        if (e < e1) {
            int r = row[e], c = col[e];
            rr[i] = r; cc[i] = c;
            atomicAdd(&hc[c >> 8], 1);
            atomicAdd(&hr[r >> 8], 1);
        }
    }
    __syncthreads();
    for (int i = t; i < NB; i += PT) {
        bc[i] = (hc[i] > 0) ? (i * CAP + atomicAdd(&colCursor[i], hc[i])) : 0;
        br[i] = (hr[i] > 0) ? (i * CAP + atomicAdd(&rowCursor[i], hr[i])) : 0;
    }
    __syncthreads();
    #pragma unroll
    for (int i = 0; i < EPT; ++i) {
        int e = e0 + t + i * PT;
        if (e < e1) {
            int r = rr[i], c = cc[i];
            int pc = atomicAdd(&bc[c >> 8], 1);
            S[pc] = ((u32)r << 8) | (u32)(c & 255);
            int pr = atomicAdd(&br[r >> 8], 1);
            Sr[pr] = (u8)(r & 255);
        }
    }
}

// K_B: blocks 0..NB-1 fine-CSR; NB..2NB-1 degree/dinv; 2NB.. label_fill.
__global__ void csr_fill_kernel(const u32* __restrict__ S, const u8* __restrict__ Sr,
                                const int* __restrict__ colCursor, const int* __restrict__ rowCursor,
                                int* __restrict__ s_beg, int* __restrict__ s_end,
                                u16* __restrict__ srcrow, float* __restrict__ dinv,
                                const int* __restrict__ label, const int* __restrict__ labCnt,
                                int* __restrict__ labOffset, int* __restrict__ nodeByLabel) {
    __shared__ int h[CPB], cur[CPB], sc[CPB];
    __shared__ int h8[8], base8[8], c28[8];
    int t = threadIdx.x;
    if (blockIdx.x >= 2 * NB) {
        // ---- label_fill branch (98 blocks x 512 threads) ----
        if (t < 8) { h8[t] = 0; c28[t] = 0; }
        __syncthreads();
        int n = (blockIdx.x - 2 * NB) * PT + t;
        int l = 0;
        if (n < N_NODES) { l = label[n]; atomicAdd(&h8[l], 1); }
        __syncthreads();
        if (t < 8 && h8[t] > 0) {
            int lb = 0;                          // labBase[l] = prefix of labCnt
            for (int i = 0; i < t; ++i) lb += labCnt[i];
            base8[t] = lb + atomicAdd(&labOffset[t], h8[t]);
        }
        __syncthreads();
        if (n < N_NODES) {
            int pos = base8[l] + atomicAdd(&c28[l], 1);
            nodeByLabel[pos] = n;
        }
        return;
    }
    if (blockIdx.x >= NB) {
        // ---- degree branch: LDS histogram of Sr bucket -> dinv ----
        int b = blockIdx.x - NB;
        if (t < CPB) h[t] = 0;
        __syncthreads();
        int e0 = b * CAP, e1 = b * CAP + rowCursor[b];
        for (int e = e0 + t; e < e1; e += PT) atomicAdd(&h[Sr[e]], 1);
        __syncthreads();
        if (t < CPB) {
            int n = b * CPB + t;
            if (n < N_NODES) dinv[n] = rsqrtf((float)(h[t] + 1));
        }
        return;
    }
    // ---- fine-CSR branch ----
    int b = blockIdx.x;
    if (t < CPB) h[t] = 0;
    __syncthreads();
    int e0 = b * CAP, e1 = b * CAP + colCursor[b];
    for (int e = e0 + t; e < e1; e += PT) atomicAdd(&h[S[e] & 255u], 1);
    __syncthreads();
    if (t < CPB) sc[t] = h[t];
    __syncthreads();
    for (int off = 1; off < CPB; off <<= 1) {
        int v = 0, a = 0;
        if (t < CPB) { v = sc[t]; a = (t >= off) ? sc[t - off] : 0; }
        __syncthreads();
        if (t < CPB) sc[t] = v + a;
        __syncthreads();
    }
    if (t < CPB) {
        int base = (t == 0) ? 0 : sc[t - 1];
        int gcol = b * CPB + t;
        if (gcol < N_NODES) {
            s_beg[gcol] = e0 + base;
            s_end[gcol] = e0 + base + h[t];
        }
        cur[t] = base;
    }
    __syncthreads();
    for (int e = e0 + t; e < e1; e += PT) {
        u32 v = S[e];
        int pos = atomicAdd(&cur[v & 255u], 1);
        srcrow[e0 + pos] = (u16)(v >> 8);
    }
}

// K6: label-grouped node transform -> bf16 messages.
// ONE wave per block (64 threads), 2 output channels per thread (t, t+64):
// every LDS broadcast read serves the whole block exactly once (r10 lesson —
// the 2-wave version issued each broadcast twice).
__global__ void node_msg_kernel(const float* __restrict__ x,
                                const int* __restrict__ cnt,
                                const int* __restrict__ label,
                                const float* __restrict__ dinv,
                                const float* __restrict__ W,
                                const float* __restrict__ Wid,
                                const int* __restrict__ nodeByLabel,
                                __hip_bfloat16* __restrict__ msgb) {
    __shared__ float xsT[C_DIM][GB];       // [k][g], 4 KB
    __shared__ int nid[GB], lab[GB], cc[GB];
    int t = threadIdx.x;                   // 0..63
    int t2 = t + 64;
    if (t < GB) {
        int n = nodeByLabel[blockIdx.x * GB + t];
        nid[t] = n; lab[t] = label[n]; cc[t] = cnt[n];
    }
    __syncthreads();
    #pragma unroll
    for (int g = 0; g < GB; ++g) {
        xsT[t][g]  = __builtin_nontemporal_load(x + (size_t)nid[g] * C_DIM + t);
        xsT[t2][g] = __builtin_nontemporal_load(x + (size_t)nid[g] * C_DIM + t2);
    }
    __syncthreads();
    for (int g = 0; g < GB; ++g) {          // ego update (~4% of nodes)
        int c = cc[g];
        if (c > 0) {
            float a0 = 0.f, a1 = 0.f;
            #pragma unroll 8
            for (int k = 0; k < C_DIM; ++k) {
                float xv = xsT[k][g];
                a0 += xv * W[k * C_DIM + t];
                a1 += xv * W[k * C_DIM + t2];
            }
            __syncthreads();
            xsT[t][g]  += (float)c * a0;
            xsT[t2][g] += (float)c * a1;
            __syncthreads();
        }
    }
    float res0[GB], res1[GB];
    #pragma unroll
    for (int g = 0; g < GB; ++g) { res0[g] = xsT[t][g]; res1[g] = xsT[t2][g]; }
    if (lab[0] == lab[GB - 1]) {
        int L = lab[0];
        if (L > 0) {
            const float* Wl = Wid + (size_t)(L - 1) * C_DIM * C_DIM;
            float acc0[GB], acc1[GB];
            #pragma unroll
            for (int g = 0; g < GB; ++g) { acc0[g] = 0.f; acc1[g] = 0.f; }
            for (int k = 0; k < C_DIM; ++k) {
                float w0 = Wl[k * C_DIM + t];
                float w1 = Wl[k * C_DIM + t2];
                f32x4 xv0 = *(const f32x4*)&xsT[k][0];   // broadcast b128
                f32x4 xv1 = *(const f32x4*)&xsT[k][4];   // broadcast b128
                acc0[0] += xv0.x * w0; acc0[1] += xv0.y * w0;
                acc0[2] += xv0.z * w0; acc0[3] += xv0.w * w0;
                acc0[4] += xv1.x * w0; acc0[5] += xv1.y * w0;
                acc0[6] += xv1.z * w0; acc0[7] += xv1.w * w0;
                acc1[0] += xv0.x * w1; acc1[1] += xv0.y * w1;
                acc1[2] += xv0.z * w1; acc1[3] += xv0.w * w1;
                acc1[4] += xv1.x * w1; acc1[5] += xv1.y * w1;
                acc1[6] += xv1.z * w1; acc1[7] += xv1.w * w1;
            }
            #pragma unroll
            for (int g = 0; g < GB; ++g) { res0[g] += acc0[g]; res1[g] += acc1[g]; }
        }
    } else {
        for (int g = 0; g < GB; ++g) {
            int L = lab[g];
            if (L > 0) {
                const float* Wl = Wid + (size_t)(L - 1) * C_DIM * C_DIM;
                float a0 = 0.f, a1 = 0.f;
                #pragma unroll 8
                for (int k = 0; k < C_DIM; ++k) {
                    float xv = xsT[k][g];
                    a0 += xv * Wl[k * C_DIM + t];
                    a1 += xv * Wl[k * C_DIM + t2];
                }
                res0[g] += a0; res1[g] += a1;
            }
        }
    }
    #pragma unroll
    for (int g = 0; g < GB; ++g) {
        int n = nid[g];
        float di = dinv[n];
        msgb[(size_t)n * C_DIM + t]  = __float2bfloat16(di * res0[g]);
        msgb[(size_t)n * C_DIM + t2] = __float2bfloat16(di * res1[g]);
    }
}

// K7: gather + finalize (single-pass, r8 proven form). One wave per dest node;
// 4 edges in flight per wave. lane = (g,q): g = edge slot, q = channel quad.
__global__ void gather_kernel(const int* __restrict__ s_beg, const int* __restrict__ s_end,
                              const u16* __restrict__ srcrow,
                              const float* __restrict__ dinv,
                              const u32* __restrict__ m32,   // bf16x2-packed msg
                              float* __restrict__ out) {
    int wid  = threadIdx.x >> 6;
    int lane = threadIdx.x & 63;
    int g = lane >> 4;
    int q = lane & 15;
    int c = blockIdx.x * 4 + wid;
    int e0 = s_beg[c], e1 = s_end[c];
    const uint4* m4 = (const uint4*)m32;   // one node = 16 uint4

    float a0[4], a1[4];
    #pragma unroll
    for (int k = 0; k < 4; ++k) { a0[k] = 0.f; a1[k] = 0.f; }

    #define ACC4(U)                                                          \
        a0[0] += __uint_as_float((U).x << 16); a1[0] += __uint_as_float((U).x & 0xffff0000u); \
        a0[1] += __uint_as_float((U).y << 16); a1[1] += __uint_as_float((U).y & 0xffff0000u); \
        a0[2] += __uint_as_float((U).z << 16); a1[2] += __uint_as_float((U).z & 0xffff0000u); \
        a0[3] += __uint_as_float((U).w << 16); a1[3] += __uint_as_float((U).w & 0xffff0000u);

    int e = e0;
    for (; e + 8 <= e1; e += 8) {
        u32 r0 = srcrow[e + g];
        u32 r1 = srcrow[e + 4 + g];
        uint4 u0 = m4[r0 * 16u + (u32)q];
        uint4 u1 = m4[r1 * 16u + (u32)q];
        ACC4(u0);
        ACC4(u1);
    }
    if (e + 4 <= e1) {
        u32 r0 = srcrow[e + g];
        uint4 u0 = m4[r0 * 16u + (u32)q];
        ACC4(u0);
        e += 4;
    }
    if (g == 0) {
        // self-loop message (counted once via edge-slot 0 only)
        uint4 us = m4[(u32)c * 16u + (u32)q];
        ACC4(us);
        // tail (< 4 remaining edges)
        for (; e < e1; ++e) {
            u32 r = srcrow[e];
            uint4 u = m4[r * 16u + (u32)q];
            ACC4(u);
        }
    }
    #undef ACC4

    // reduce the 4 edge-slot groups: lanes l, l^16, l^32, l^48 hold the same quad q
    #pragma unroll
    for (int k = 0; k < 4; ++k) {
        a0[k] += __shfl_xor(a0[k], 16);
        a0[k] += __shfl_xor(a0[k], 32);
        a1[k] += __shfl_xor(a1[k], 16);
        a1[k] += __shfl_xor(a1[k], 32);
    }

    if (lane < 16) {
        float di = dinv[c];
        f32x4 o0, o1;
        o0.x = di * a0[0]; o0.y = di * a1[0]; o0.z = di * a0[1]; o0.w = di * a1[1];
        o1.x = di * a0[2]; o1.y = di * a1[2]; o1.z = di * a0[3]; o1.w = di * a1[3];
        f32x4* op = (f32x4*)(out + ((size_t)c << 7)) + (q << 1);
        __builtin_nontemporal_store(o0, op);
        __builtin_nontemporal_store(o1, op + 1);
    }
}

extern "C" void kernel_launch(void* const* d_in, const int* in_sizes, int n_in,
                              void* d_out, int out_size, void* d_ws, size_t ws_size,
                              hipStream_t stream) {
    const float* x     = (const float*)d_in[0];
    const int*   edge  = (const int*)d_in[1];   // [2][E]
    const int*   id    = (const int*)d_in[2];
    const int*   label = (const int*)d_in[3];
    const float* W     = (const float*)d_in[4];
    const float* Wid   = (const float*)d_in[5];
    float*       out   = (float*)d_out;

    const int* row = edge;
    const int* col = edge + E_EDGES;

    // ws layout:
    // msgb[N*C] bf16 | S[NB*CAP] u32 | srcrow[NB*CAP] u16 | Sr[NB*CAP] u8 |
    // s_beg[N] | s_end[N] | nodeByLabel[N] | dinv[N] f32 |
    // ZERO{ cnt[N] | labCnt[8] | labOffset[8] | colCursor[NB] | rowCursor[NB] }
    __hip_bfloat16* msgb = (__hip_bfloat16*)d_ws;
    u32* S           = (u32*)(msgb + (size_t)N_NODES * C_DIM);
    u16* srcrow      = (u16*)(S + (size_t)NB * CAP);
    u8*  Sr          = (u8*)(srcrow + (size_t)NB * CAP);
    int* s_beg       = (int*)(Sr + (size_t)NB * CAP);
    int* s_end       = s_beg + N_NODES;
    int* nodeByLabel = s_end + N_NODES;
    float* dinv      = (float*)(nodeByLabel + N_NODES);
    int* cnt         = (int*)(dinv + N_NODES);
    int* labCnt      = cnt + N_NODES;
    int* labOffset   = labCnt + 8;
    int* colCursor   = labOffset + 8;
    int* rowCursor   = colCursor + NB;

    hipMemsetAsync(cnt, 0, ((size_t)N_NODES + 16 + 2 * NB) * sizeof(int), stream);

    part_hist_kernel<<<NP + NLB, PT, 0, stream>>>(row, col, label, id,
                                                  colCursor, rowCursor, S, Sr, labCnt, cnt);
    csr_fill_kernel <<<2 * NB + NLB, PT, 0, stream>>>(S, Sr, colCursor, rowCursor,
                                                      s_beg, s_end, srcrow, dinv,
                                                      label, labCnt, labOffset, nodeByLabel);
    node_msg_kernel <<<N_NODES / GB, 64, 0, stream>>>(x, cnt, label, dinv, W, Wid,
                                                      nodeByLabel, msgb);
    gather_kernel   <<<N_NODES / 4, 256, 0, stream>>>(s_beg, s_end, srcrow, dinv,
                                                      (const u32*)msgb, out);
}